// Round 7
// baseline (349.745 us; speedup 1.0000x reference)
//
#include <hip/hip_runtime.h>
#include <hip/hip_bf16.h>

typedef unsigned short ushort_t;
typedef __attribute__((ext_vector_type(8))) short short8;
typedef __attribute__((ext_vector_type(4))) float f32x4;

// ---------- f32 -> bf16 (raw bits, RNE) ----------
__device__ __forceinline__ ushort_t f2bf(float f) {
    union { float f; unsigned int u; } v; v.f = f;
    unsigned int r = v.u + 0x7fffu + ((v.u >> 16) & 1u);
    return (ushort_t)(r >> 16);
}

// ---------- async global->LDS, 16B/lane, dest = base + lane*16 ----------
__device__ __forceinline__ void async16(const ushort_t* g, ushort_t* l) {
    __builtin_amdgcn_global_load_lds((const __attribute__((address_space(1))) void*)g,
                                     (__attribute__((address_space(3))) void*)l,
                                     16, 0, 0);
}

// =====================================================================
__global__ void cvt_bf16(const float* __restrict__ src, ushort_t* __restrict__ dst) {
    int i = (blockIdx.x * 256 + threadIdx.x) * 8;
    float4 f0 = *(const float4*)(src + i);
    float4 f1 = *(const float4*)(src + i + 4);
    union { uint4 v; ushort_t e[8]; } d;
    d.e[0]=f2bf(f0.x); d.e[1]=f2bf(f0.y); d.e[2]=f2bf(f0.z); d.e[3]=f2bf(f0.w);
    d.e[4]=f2bf(f1.x); d.e[5]=f2bf(f1.y); d.e[6]=f2bf(f1.z); d.e[7]=f2bf(f1.w);
    *(uint4*)(dst + i) = d.v;
}

// Transpose fp32 [R][C] -> bf16 [C][R]. Tile 32x32, block (32,8).
__global__ void transpose_w(const float* __restrict__ src, ushort_t* __restrict__ dst,
                            int R, int C) {
    __shared__ ushort_t tile[32][33];
    const int bx = blockIdx.x * 32, by = blockIdx.y * 32;
    const int tx = threadIdx.x, ty = threadIdx.y;
    #pragma unroll
    for (int i = 0; i < 32; i += 8)
        tile[ty + i][tx] = f2bf(src[(size_t)(by + ty + i) * C + bx + tx]);
    __syncthreads();
    #pragma unroll
    for (int i = 0; i < 32; i += 8)
        dst[(size_t)(bx + ty + i) * R + by + tx] = tile[tx][ty + i];
}

// Transpose V out of kqv: per (b,h) [2048 t][64 d] -> vT[b][h][64 d][2048 t].
__global__ void transpose_v(const ushort_t* __restrict__ kqv, ushort_t* __restrict__ vT) {
    __shared__ ushort_t tile[32][33];
    const int bh = blockIdx.z;
    const int b = bh >> 4, h = bh & 15;
    const int t0 = blockIdx.x * 32, d0 = blockIdx.y * 32;
    const int tx = threadIdx.x, ty = threadIdx.y;
    #pragma unroll
    for (int i = 0; i < 32; i += 8)
        tile[ty + i][tx] = kqv[(size_t)(b * 2048 + t0 + ty + i) * 3072 + 2048 + h * 64 + d0 + tx];
    __syncthreads();
    #pragma unroll
    for (int i = 0; i < 32; i += 8)
        vT[((size_t)bh * 64 + d0 + ty + i) * 2048 + t0 + tx] = tile[tx][ty + i];
}

// =====================================================================
// GEMM (m97-style): C[M,N] = A[M,K] * Bt[N,K]^T, bf16 in, fp32 acc.
// =====================================================================
template <bool CF32>
__global__ __launch_bounds__(256, 2)
void gemm_bt(const ushort_t* __restrict__ A, const ushort_t* __restrict__ Bt,
             void* __restrict__ Cv, int M, int N, int K) {
    constexpr int BK = 32;
    __shared__ ushort_t As[128 * BK];
    __shared__ ushort_t Bs[128 * BK];

    const int tid  = threadIdx.x;
    const int wave = tid >> 6;
    const int lane = tid & 63;
    const int quad = lane >> 4;
    const int l16  = lane & 15;
    const int m0 = blockIdx.x * 128;
    const int n0 = blockIdx.y * 128;
    const int wm = (wave >> 1) * 64;
    const int wn = (wave & 1) * 64;
    const int rA = (lane >> 2);
    const int cA = (lane & 3) * 8;

    f32x4 acc[4][4] = {};

    for (int k0 = 0; k0 < K; k0 += BK) {
        __syncthreads();
        #pragma unroll
        for (int u = 0; u < 2; ++u) {
            int c = wave * 2 + u;
            int row = c * 16 + rA;
            async16(A  + (size_t)(m0 + row) * K + k0 + cA, As + c * 512);
            async16(Bt + (size_t)(n0 + row) * K + k0 + cA, Bs + c * 512);
        }
        __syncthreads();

        short8 af[4], bf[4];
        #pragma unroll
        for (int mt = 0; mt < 4; ++mt)
            af[mt] = *(const short8*)(As + (wm + mt * 16 + l16) * BK + quad * 8);
        #pragma unroll
        for (int nt = 0; nt < 4; ++nt)
            bf[nt] = *(const short8*)(Bs + (wn + nt * 16 + l16) * BK + quad * 8);

        #pragma unroll
        for (int mt = 0; mt < 4; ++mt)
            #pragma unroll
            for (int nt = 0; nt < 4; ++nt)
                acc[mt][nt] = __builtin_amdgcn_mfma_f32_16x16x32_bf16(
                    af[mt], bf[nt], acc[mt][nt], 0, 0, 0);
    }

    #pragma unroll
    for (int mt = 0; mt < 4; ++mt) {
        #pragma unroll
        for (int r = 0; r < 4; ++r) {
            int row = m0 + wm + mt * 16 + quad * 4 + r;
            if constexpr (CF32) {
                float* op = (float*)Cv + (size_t)row * N + n0 + wn + l16;
                #pragma unroll
                for (int nt = 0; nt < 4; ++nt) op[nt * 16] = acc[mt][nt][r];
            } else {
                ushort_t* op = (ushort_t*)Cv + (size_t)row * N + n0 + wn + l16;
                #pragma unroll
                for (int nt = 0; nt < 4; ++nt) op[nt * 16] = f2bf(acc[mt][nt][r]);
            }
        }
    }
}

// =====================================================================
// Flash attention v5: k-split waves. Each wave: all 64 q-rows, 32 of the
// 128 tile-keys -> K/V fragment LDS reads drop 4x (DS pipe was binding).
// Partial O / row-sums add across waves once at kernel end (softmax-lite
// has no rescale coupling). LDS 52 KB: Ks 16K | Vs 16K | Ps 20K; the
// same space is reused as fp32 reduction scratch at the end.
// =====================================================================
__global__ __launch_bounds__(256, 3)
void attn_kernel(const ushort_t* __restrict__ kqv, const ushort_t* __restrict__ vT,
                 ushort_t* __restrict__ aout) {
    constexpr int T = 2048;
    constexpr float SC = 0.18033688011112042f;  // (1/8) * log2(e)

    __shared__ ushort_t smem[26624];            // 52 KB
    ushort_t* Ks = smem;                        // [128 key][64 d], swizzled chunks
    ushort_t* Vs = smem + 8192;                 // [64 d][128 key], swizzled chunks
    ushort_t* Ps = smem + 16384;                // 4 waves x [64 m][40] (32 keys + pad)

    const int tid  = threadIdx.x;
    const int wave = tid >> 6;
    const int lane = tid & 63;
    const int quad = lane >> 4;
    const int l16  = lane & 15;

    // XCD swizzle: all 32 q-tiles of one bh share an XCD.
    const int lin = blockIdx.x;
    const int qt  = (lin >> 3) & 31;
    const int bh  = ((lin >> 8) << 3) | (lin & 7);
    const int b   = bh >> 4, h = bh & 15;
    const int q0  = qt * 64;
    const size_t rowBase = (size_t)b * T;

    // Q A-frags for ALL 4 m-tiles (m = l16, k = kh*32 + quad*8 + j)
    short8 qf[4][2];
    #pragma unroll
    for (int mt = 0; mt < 4; ++mt) {
        const ushort_t* qp = kqv + (rowBase + q0 + mt * 16 + l16) * 3072 + 1024 + h * 64;
        qf[mt][0] = *(const short8*)(qp + quad * 8);
        qf[mt][1] = *(const short8*)(qp + 32 + quad * 8);
    }

    const ushort_t* kbase = kqv + rowBase * 3072 + h * 64;
    const ushort_t* vbase = vT + (size_t)bh * 64 * 2048;
    ushort_t* pw = Ps + wave * 2560;

    f32x4 O[4][4] = {};
    float lrow[4][4] = {};

    for (int kk = 0; kk < T; kk += 128) {
        __syncthreads();
        #pragma unroll
        for (int u = 0; u < 4; ++u) {
            int g = u * 256 + tid;
            int key = g >> 3, pos = g & 7;
            int c = pos ^ (key & 7);
            async16(kbase + (size_t)(kk + key) * 3072 + c * 8, Ks + g * 8);
            int d = g >> 4, pos2 = g & 15;
            int c2 = (pos2 & 8) | ((pos2 ^ d) & 7);
            async16(vbase + (size_t)d * 2048 + kk + c2 * 8, Vs + g * 8);
        }
        __syncthreads();

        // K fragments for this wave's keys [wave*32, +32)
        short8 kf[2][2];
        #pragma unroll
        for (int ntt = 0; ntt < 2; ++ntt) {
            int key = wave * 32 + ntt * 16 + l16;
            #pragma unroll
            for (int kh = 0; kh < 2; ++kh) {
                int pos = (kh * 4 + quad) ^ (l16 & 7);
                kf[ntt][kh] = *(const short8*)(Ks + key * 64 + pos * 8);
            }
        }

        // S (64q x 32k), softmax-lite, P -> LDS
        #pragma unroll
        for (int mt = 0; mt < 4; ++mt) {
            f32x4 s0 = {0.f, 0.f, 0.f, 0.f}, s1 = {0.f, 0.f, 0.f, 0.f};
            s0 = __builtin_amdgcn_mfma_f32_16x16x32_bf16(qf[mt][0], kf[0][0], s0, 0, 0, 0);
            s0 = __builtin_amdgcn_mfma_f32_16x16x32_bf16(qf[mt][1], kf[0][1], s0, 0, 0, 0);
            s1 = __builtin_amdgcn_mfma_f32_16x16x32_bf16(qf[mt][0], kf[1][0], s1, 0, 0, 0);
            s1 = __builtin_amdgcn_mfma_f32_16x16x32_bf16(qf[mt][1], kf[1][1], s1, 0, 0, 0);
            #pragma unroll
            for (int r = 0; r < 4; ++r) {
                float p0 = __builtin_amdgcn_exp2f(s0[r] * SC);
                float p1 = __builtin_amdgcn_exp2f(s1[r] * SC);
                lrow[mt][r] += p0 + p1;
                int m = mt * 16 + quad * 4 + r;
                pw[m * 40 + l16]      = f2bf(p0);
                pw[m * 40 + 16 + l16] = f2bf(p1);
            }
        }

        // V^T fragments (loaded late to cap liveness): d = dt*16+l16, k = wave keys
        short8 vf[4];
        #pragma unroll
        for (int dt = 0; dt < 4; ++dt) {
            int d = dt * 16 + l16;
            int c = wave * 4 + quad;
            int pos = (c & 8) | ((c ^ d) & 7);
            vf[dt] = *(const short8*)(Vs + d * 128 + pos * 8);
        }
        asm volatile("s_waitcnt lgkmcnt(0)" ::: "memory");

        // O += P V over this wave's 32 keys
        #pragma unroll
        for (int mt = 0; mt < 4; ++mt) {
            short8 pf = *(const short8*)(pw + (mt * 16 + l16) * 40 + quad * 8);
            #pragma unroll
            for (int dt = 0; dt < 4; ++dt)
                O[mt][dt] = __builtin_amdgcn_mfma_f32_16x16x32_bf16(pf, vf[dt], O[mt][dt], 0, 0, 0);
        }
    }

    // ---- epilogue: cross-wave reduction ----
    #pragma unroll
    for (int mt = 0; mt < 4; ++mt)
        #pragma unroll
        for (int r = 0; r < 4; ++r) {
            float s = lrow[mt][r];
            #pragma unroll
            for (int off = 1; off < 16; off <<= 1) s += __shfl_xor(s, off, 64);
            lrow[mt][r] = s;
        }

    __syncthreads();                       // done with Ks/Vs/Ps: reuse as scratch
    float* Osc  = (float*)smem;            // 4 waves x 32 rows x 66 floats
    float* lsum = (float*)smem + 8448;     // 4 waves x 64 rows

    if (l16 == 0) {
        #pragma unroll
        for (int mt = 0; mt < 4; ++mt)
            #pragma unroll
            for (int r = 0; r < 4; ++r)
                lsum[wave * 64 + mt * 16 + quad * 4 + r] = lrow[mt][r];
    }

    #pragma unroll
    for (int half = 0; half < 2; ++half) {
        if (half) __syncthreads();
        // write partial O rows [half*32, +32) to scratch
        #pragma unroll
        for (int mh = 0; mh < 2; ++mh) {
            int mt = half * 2 + mh;
            #pragma unroll
            for (int r = 0; r < 4; ++r) {
                int rl = mh * 16 + quad * 4 + r;
                #pragma unroll
                for (int dt = 0; dt < 4; ++dt)
                    Osc[wave * 2112 + rl * 66 + dt * 16 + l16] = O[mt][dt][r];
            }
        }
        __syncthreads();
        // each lane reduces one (row, 8-col) strip across the 4 waves
        int rl = wave * 8 + (lane >> 3);
        int c0 = (lane & 7) * 8;
        int m  = half * 32 + rl;
        float s = lsum[m] + lsum[64 + m] + lsum[128 + m] + lsum[192 + m];
        float inv = 1.f / s;
        float acc[8] = {};
        #pragma unroll
        for (int w = 0; w < 4; ++w)
            #pragma unroll
            for (int j = 0; j < 8; ++j)
                acc[j] += Osc[w * 2112 + rl * 66 + c0 + j];
        union { uint4 v; ushort_t e[8]; } o;
        #pragma unroll
        for (int j = 0; j < 8; ++j) o.e[j] = f2bf(acc[j] * inv);
        *(uint4*)(aout + (rowBase + q0 + m) * 1024 + h * 64 + c0) = o.v;
    }
}

// =====================================================================
extern "C" void kernel_launch(void* const* d_in, const int* in_sizes, int n_in,
                              void* d_out, int out_size, void* d_ws, size_t ws_size,
                              hipStream_t stream) {
    const float* x     = (const float*)d_in[0];
    const float* Wkqv  = (const float*)d_in[1];
    const float* Wproj = (const float*)d_in[2];
    float* out = (float*)d_out;

    constexpr int M = 8192, K = 1024;
    char* ws = (char*)d_ws;
    ushort_t* kqv    = (ushort_t*)(ws);               // 48 MB
    ushort_t* vT     = (ushort_t*)(ws + 50331648);    // 16 MB
    ushort_t* xb     = (ushort_t*)(ws + 67108864);    // 16 MB (aliases aout)
    ushort_t* aout   = xb;
    ushort_t* WkqvT  = (ushort_t*)(ws + 83886080);    // 6 MB
    ushort_t* WprojT = (ushort_t*)(ws + 90177536);    // 2 MB

    cvt_bf16<<<4096, 256, 0, stream>>>(x, xb);
    transpose_w<<<dim3(96, 32), dim3(32, 8), 0, stream>>>(Wkqv, WkqvT, 1024, 3072);
    transpose_w<<<dim3(32, 32), dim3(32, 8), 0, stream>>>(Wproj, WprojT, 1024, 1024);

    gemm_bt<false><<<dim3(M / 128, 3072 / 128), 256, 0, stream>>>(xb, WkqvT, kqv, M, 3072, K);
    transpose_v<<<dim3(64, 2, 64), dim3(32, 8), 0, stream>>>(kqv, vT);
    attn_kernel<<<2048, 256, 0, stream>>>(kqv, vT, aout);
    gemm_bt<true><<<dim3(M / 128, 1024 / 128), 256, 0, stream>>>(aout, WprojT, out, M, 1024, K);
}

// Round 8
// 298.058 us; speedup vs baseline: 1.1734x; 1.1734x over previous
//
#include <hip/hip_runtime.h>
#include <hip/hip_bf16.h>

typedef unsigned short ushort_t;
typedef __attribute__((ext_vector_type(8))) short short8;
typedef __attribute__((ext_vector_type(4))) float f32x4;

// ---------- f32 -> bf16 (raw bits, RNE) ----------
__device__ __forceinline__ ushort_t f2bf(float f) {
    union { float f; unsigned int u; } v; v.f = f;
    unsigned int r = v.u + 0x7fffu + ((v.u >> 16) & 1u);
    return (ushort_t)(r >> 16);
}

// ---------- async global->LDS, 16B/lane, dest = base + lane*16 ----------
__device__ __forceinline__ void async16(const ushort_t* g, ushort_t* l) {
    __builtin_amdgcn_global_load_lds((const __attribute__((address_space(1))) void*)g,
                                     (__attribute__((address_space(3))) void*)l,
                                     16, 0, 0);
}

// =====================================================================
__global__ void cvt_bf16(const float* __restrict__ src, ushort_t* __restrict__ dst) {
    int i = (blockIdx.x * 256 + threadIdx.x) * 8;
    float4 f0 = *(const float4*)(src + i);
    float4 f1 = *(const float4*)(src + i + 4);
    union { uint4 v; ushort_t e[8]; } d;
    d.e[0]=f2bf(f0.x); d.e[1]=f2bf(f0.y); d.e[2]=f2bf(f0.z); d.e[3]=f2bf(f0.w);
    d.e[4]=f2bf(f1.x); d.e[5]=f2bf(f1.y); d.e[6]=f2bf(f1.z); d.e[7]=f2bf(f1.w);
    *(uint4*)(dst + i) = d.v;
}

// Transpose fp32 [R][C] -> bf16 [C][R]. Tile 32x32, block (32,8).
__global__ void transpose_w(const float* __restrict__ src, ushort_t* __restrict__ dst,
                            int R, int C) {
    __shared__ ushort_t tile[32][33];
    const int bx = blockIdx.x * 32, by = blockIdx.y * 32;
    const int tx = threadIdx.x, ty = threadIdx.y;
    #pragma unroll
    for (int i = 0; i < 32; i += 8)
        tile[ty + i][tx] = f2bf(src[(size_t)(by + ty + i) * C + bx + tx]);
    __syncthreads();
    #pragma unroll
    for (int i = 0; i < 32; i += 8)
        dst[(size_t)(bx + ty + i) * R + by + tx] = tile[tx][ty + i];
}

// Transpose V out of kqv: per (b,h) [2048 t][64 d] -> vT[b][h][64 d][2048 t].
__global__ void transpose_v(const ushort_t* __restrict__ kqv, ushort_t* __restrict__ vT) {
    __shared__ ushort_t tile[32][33];
    const int bh = blockIdx.z;
    const int b = bh >> 4, h = bh & 15;
    const int t0 = blockIdx.x * 32, d0 = blockIdx.y * 32;
    const int tx = threadIdx.x, ty = threadIdx.y;
    #pragma unroll
    for (int i = 0; i < 32; i += 8)
        tile[ty + i][tx] = kqv[(size_t)(b * 2048 + t0 + ty + i) * 3072 + 2048 + h * 64 + d0 + tx];
    __syncthreads();
    #pragma unroll
    for (int i = 0; i < 32; i += 8)
        vT[((size_t)bh * 64 + d0 + ty + i) * 2048 + t0 + tx] = tile[tx][ty + i];
}

// =====================================================================
// GEMM (m97-style): C[M,N] = A[M,K] * Bt[N,K]^T, bf16 in, fp32 acc.
// =====================================================================
template <bool CF32>
__global__ __launch_bounds__(256, 2)
void gemm_bt(const ushort_t* __restrict__ A, const ushort_t* __restrict__ Bt,
             void* __restrict__ Cv, int M, int N, int K) {
    constexpr int BK = 32;
    __shared__ ushort_t As[128 * BK];
    __shared__ ushort_t Bs[128 * BK];

    const int tid  = threadIdx.x;
    const int wave = tid >> 6;
    const int lane = tid & 63;
    const int quad = lane >> 4;
    const int l16  = lane & 15;
    const int m0 = blockIdx.x * 128;
    const int n0 = blockIdx.y * 128;
    const int wm = (wave >> 1) * 64;
    const int wn = (wave & 1) * 64;
    const int rA = (lane >> 2);
    const int cA = (lane & 3) * 8;

    f32x4 acc[4][4] = {};

    for (int k0 = 0; k0 < K; k0 += BK) {
        __syncthreads();
        #pragma unroll
        for (int u = 0; u < 2; ++u) {
            int c = wave * 2 + u;
            int row = c * 16 + rA;
            async16(A  + (size_t)(m0 + row) * K + k0 + cA, As + c * 512);
            async16(Bt + (size_t)(n0 + row) * K + k0 + cA, Bs + c * 512);
        }
        __syncthreads();

        short8 af[4], bf[4];
        #pragma unroll
        for (int mt = 0; mt < 4; ++mt)
            af[mt] = *(const short8*)(As + (wm + mt * 16 + l16) * BK + quad * 8);
        #pragma unroll
        for (int nt = 0; nt < 4; ++nt)
            bf[nt] = *(const short8*)(Bs + (wn + nt * 16 + l16) * BK + quad * 8);

        #pragma unroll
        for (int mt = 0; mt < 4; ++mt)
            #pragma unroll
            for (int nt = 0; nt < 4; ++nt)
                acc[mt][nt] = __builtin_amdgcn_mfma_f32_16x16x32_bf16(
                    af[mt], bf[nt], acc[mt][nt], 0, 0, 0);
    }

    #pragma unroll
    for (int mt = 0; mt < 4; ++mt) {
        #pragma unroll
        for (int r = 0; r < 4; ++r) {
            int row = m0 + wm + mt * 16 + quad * 4 + r;
            if constexpr (CF32) {
                float* op = (float*)Cv + (size_t)row * N + n0 + wn + l16;
                #pragma unroll
                for (int nt = 0; nt < 4; ++nt) op[nt * 16] = acc[mt][nt][r];
            } else {
                ushort_t* op = (ushort_t*)Cv + (size_t)row * N + n0 + wn + l16;
                #pragma unroll
                for (int nt = 0; nt < 4; ++nt) op[nt * 16] = f2bf(acc[mt][nt][r]);
            }
        }
    }
}

// =====================================================================
// Flash attention v6: q-split waves, 32 q-rows/wave (2 m-tiles),
// 128 q/block, 64-key tiles. K/V fragment reads amortized over 2x
// q-rows; staging per q-row halved. No cross-wave coupling (each wave
// owns its rows end-to-end). LDS 32 KB: Ks 8K | Vs 8K | Ps 16K.
// VGPR budget ~130 -> no spill at __launch_bounds__(256,3).
// =====================================================================
__global__ __launch_bounds__(256, 3)
void attn_kernel(const ushort_t* __restrict__ kqv, const ushort_t* __restrict__ vT,
                 ushort_t* __restrict__ aout) {
    constexpr int T = 2048;
    constexpr float SC = 0.18033688011112042f;  // (1/8) * log2(e)

    __shared__ ushort_t smem[16384];            // 32 KB
    ushort_t* Ks = smem;                        // [64 key][64 d], chunk pos = c ^ (key&7)
    ushort_t* Vs = smem + 4096;                 // [64 d][64 key], chunk pos = c ^ (d&7)
    ushort_t* Ps = smem + 8192;                 // 4 waves x [32 m][64 k], pos = c ^ (m&7)

    const int tid  = threadIdx.x;
    const int wave = tid >> 6;
    const int lane = tid & 63;
    const int quad = lane >> 4;
    const int l16  = lane & 15;

    // XCD swizzle: all 16 q-tiles of one bh share an XCD (lin&7 + lin>>7).
    const int lin = blockIdx.x;
    const int qt  = (lin >> 3) & 15;
    const int bh  = ((lin >> 7) << 3) | (lin & 7);
    const int b   = bh >> 4, h = bh & 15;
    const int q0  = qt * 128;
    const size_t rowBase = (size_t)b * T;

    // Q A-frags for this wave's 2 m-tiles (m = l16, k = quad*8+j / +32)
    short8 qf[2][2];
    #pragma unroll
    for (int mt = 0; mt < 2; ++mt) {
        const ushort_t* qp = kqv + (rowBase + q0 + wave * 32 + mt * 16 + l16) * 3072 + 1024 + h * 64;
        qf[mt][0] = *(const short8*)(qp + quad * 8);
        qf[mt][1] = *(const short8*)(qp + 32 + quad * 8);
    }

    const ushort_t* kbase = kqv + rowBase * 3072 + h * 64;
    const ushort_t* vbase = vT + (size_t)bh * 64 * 2048;
    ushort_t* pw = Ps + wave * 2048;

    f32x4 O[2][4] = {};
    float lrow[2][4] = {};

    for (int kk = 0; kk < T; kk += 64) {
        __syncthreads();
        // --- stage K (64x64) and V^T (64x64), swizzled 16B chunks ---
        #pragma unroll
        for (int u = 0; u < 2; ++u) {
            int g = u * 256 + tid;              // 0..511
            int row = g >> 3, pos = g & 7;
            int c = pos ^ (row & 7);
            async16(kbase + (size_t)(kk + row) * 3072 + c * 8, Ks + g * 8);
            async16(vbase + (size_t)row * 2048 + kk + c * 8, Vs + g * 8);
        }
        __syncthreads();  // vmcnt(0) drain -> LDS valid

        // --- S = Q K^T : 4 key-tiles x 2 m-tiles ---
        f32x4 S[2][4];
        #pragma unroll
        for (int nt = 0; nt < 4; ++nt) {
            int key = nt * 16 + l16;
            const ushort_t* kr = Ks + key * 64;
            short8 kf0 = *(const short8*)(kr + ((quad     ^ (l16 & 7)) * 8));
            short8 kf1 = *(const short8*)(kr + (((quad+4) ^ (l16 & 7)) * 8));
            #pragma unroll
            for (int mt = 0; mt < 2; ++mt) {
                f32x4 s = {0.f, 0.f, 0.f, 0.f};
                s = __builtin_amdgcn_mfma_f32_16x16x32_bf16(qf[mt][0], kf0, s, 0, 0, 0);
                s = __builtin_amdgcn_mfma_f32_16x16x32_bf16(qf[mt][1], kf1, s, 0, 0, 0);
                S[mt][nt] = s;
            }
        }

        // --- softmax-lite: p = exp2(S*SC); partial row sums; P -> LDS ---
        #pragma unroll
        for (int mt = 0; mt < 2; ++mt)
            #pragma unroll
            for (int nt = 0; nt < 4; ++nt) {
                int c = nt * 2 + (l16 >> 3);
                #pragma unroll
                for (int r = 0; r < 4; ++r) {
                    float p = __builtin_amdgcn_exp2f(S[mt][nt][r] * SC);
                    lrow[mt][r] += p;
                    int m = mt * 16 + quad * 4 + r;
                    int pos = c ^ (m & 7);
                    pw[m * 64 + pos * 8 + (l16 & 7)] = f2bf(p);
                }
            }
        asm volatile("s_waitcnt lgkmcnt(0)" ::: "memory");

        // --- P and V^T fragments, O += P V ---
        short8 pf[2][2];
        #pragma unroll
        for (int mt = 0; mt < 2; ++mt) {
            int m = mt * 16 + l16;
            pf[mt][0] = *(const short8*)(pw + m * 64 + ((quad     ^ (l16 & 7)) * 8));
            pf[mt][1] = *(const short8*)(pw + m * 64 + (((quad+4) ^ (l16 & 7)) * 8));
        }
        #pragma unroll
        for (int dt = 0; dt < 4; ++dt) {
            int d = dt * 16 + l16;
            const ushort_t* vr = Vs + d * 64;
            short8 vf0 = *(const short8*)(vr + ((quad     ^ (l16 & 7)) * 8));
            short8 vf1 = *(const short8*)(vr + (((quad+4) ^ (l16 & 7)) * 8));
            #pragma unroll
            for (int mt = 0; mt < 2; ++mt) {
                O[mt][dt] = __builtin_amdgcn_mfma_f32_16x16x32_bf16(pf[mt][0], vf0, O[mt][dt], 0, 0, 0);
                O[mt][dt] = __builtin_amdgcn_mfma_f32_16x16x32_bf16(pf[mt][1], vf1, O[mt][dt], 0, 0, 0);
            }
        }
    }

    // --- final row-sum reduction (16-lane), normalize, write bf16 ---
    #pragma unroll
    for (int mt = 0; mt < 2; ++mt) {
        float inv[4];
        #pragma unroll
        for (int r = 0; r < 4; ++r) {
            float s = lrow[mt][r];
            #pragma unroll
            for (int off = 1; off < 16; off <<= 1)
                s += __shfl_xor(s, off, 64);
            inv[r] = 1.f / s;
        }
        #pragma unroll
        for (int dt = 0; dt < 4; ++dt)
            #pragma unroll
            for (int r = 0; r < 4; ++r) {
                int row = q0 + wave * 32 + mt * 16 + quad * 4 + r;
                aout[(rowBase + row) * 1024 + h * 64 + dt * 16 + l16] = f2bf(O[mt][dt][r] * inv[r]);
            }
    }
}

// =====================================================================
extern "C" void kernel_launch(void* const* d_in, const int* in_sizes, int n_in,
                              void* d_out, int out_size, void* d_ws, size_t ws_size,
                              hipStream_t stream) {
    const float* x     = (const float*)d_in[0];
    const float* Wkqv  = (const float*)d_in[1];
    const float* Wproj = (const float*)d_in[2];
    float* out = (float*)d_out;

    constexpr int M = 8192, K = 1024;
    char* ws = (char*)d_ws;
    ushort_t* kqv    = (ushort_t*)(ws);               // 48 MB
    ushort_t* vT     = (ushort_t*)(ws + 50331648);    // 16 MB
    ushort_t* xb     = (ushort_t*)(ws + 67108864);    // 16 MB (aliases aout)
    ushort_t* aout   = xb;
    ushort_t* WkqvT  = (ushort_t*)(ws + 83886080);    // 6 MB
    ushort_t* WprojT = (ushort_t*)(ws + 90177536);    // 2 MB

    cvt_bf16<<<4096, 256, 0, stream>>>(x, xb);
    transpose_w<<<dim3(96, 32), dim3(32, 8), 0, stream>>>(Wkqv, WkqvT, 1024, 3072);
    transpose_w<<<dim3(32, 32), dim3(32, 8), 0, stream>>>(Wproj, WprojT, 1024, 1024);

    gemm_bt<false><<<dim3(M / 128, 3072 / 128), 256, 0, stream>>>(xb, WkqvT, kqv, M, 3072, K);
    transpose_v<<<dim3(64, 2, 64), dim3(32, 8), 0, stream>>>(kqv, vT);
    attn_kernel<<<1024, 256, 0, stream>>>(kqv, vT, aout);
    gemm_bt<true><<<dim3(M / 128, 1024 / 128), 256, 0, stream>>>(aout, WprojT, out, M, 1024, K);
}